// Round 1
// baseline (282.766 us; speedup 1.0000x reference)
//
#include <hip/hip_runtime.h>
#include <hip/hip_bf16.h>
#include <cstdint>
#include <cstddef>

// Problem constants (DeepseekV3Experts: T=1024 H=1024 I=1408 E=8 K=4)
#define NE 8
#define NT 1024
#define NK 4
#define NH 1024
#define NI 1408
#define NA (NT * NK)      // 4096 assignments
#define BM 128            // row tile (must divide padding)
#define MAXTILES 40       // >= floor(4096/128) + (NE-1) = 39
#define PADSLOTS 5120     // >= 39*128 = 4992

typedef short short8 __attribute__((ext_vector_type(8)));
typedef float f32x4 __attribute__((ext_vector_type(4)));
typedef unsigned short u16;

// Workspace layout (bytes). Total ~97.8 MB.
#define WS_HDR   0          // int[256]: counts[0..7], poff[8..16], ntiles[17], tile_e[32+j], tile_s[80+j]
#define WS_SORT  1024       // int[PADSLOTS]
#define WS_XBF   21504      // u16[NT*NH]                       (2 MB)
#define WS_GT    2118656    // u16[NE*NI*NH]  gate^T [E][I][H]  (23 MB)
#define WS_UT    25187328   // u16[NE*NI*NH]  up^T              (23 MB)
#define WS_DT    48256000   // u16[NE*NH*NI]  down^T [E][H][I]  (23 MB)
#define WS_HB    71324672   // u16[PADSLOTS*NI] h buffer        (14.4 MB)
#define WS_DTMP  85742592   // float[NA*NH]                     (16.8 MB)

__device__ __forceinline__ u16 f2b(float f) {
  union { float f; uint32_t u; } c; c.f = f;
  uint32_t u = c.u;
  return (u16)((u + 0x7FFFu + ((u >> 16) & 1u)) >> 16);  // RNE
}

__device__ __forceinline__ void llds16(const void* g, void* l) {
  __builtin_amdgcn_global_load_lds(
      (const __attribute__((address_space(1))) void*)g,
      (__attribute__((address_space(3))) void*)l, 16, 0, 0);
}

// ---------------- bucket: sort assignments by expert, build tile table ----------------
__global__ void bucket_kernel(const int* __restrict__ sel, int* __restrict__ hdr,
                              int* __restrict__ sorted) {
  __shared__ int cnt[NE], fill[NE], poff_s[NE + 1];
  int tid = threadIdx.x;
  if (tid < NE) { cnt[tid] = 0; fill[tid] = 0; }
  __syncthreads();
  for (int i = tid; i < NA; i += 256) atomicAdd(&cnt[sel[i]], 1);
  __syncthreads();
  if (tid == 0) {
    int off = 0, nt = 0;
    for (int e = 0; e < NE; ++e) {
      poff_s[e] = off;
      int tiles = (cnt[e] + BM - 1) / BM;
      for (int j = 0; j < tiles; ++j) { hdr[32 + nt] = e; hdr[80 + nt] = off + j * BM; ++nt; }
      off += tiles * BM;
    }
    poff_s[NE] = off;
    hdr[17] = nt;
    for (int e = 0; e < NE; ++e) hdr[e] = cnt[e];
    for (int e = 0; e <= NE; ++e) hdr[8 + e] = poff_s[e];
  }
  __syncthreads();
  for (int i = tid; i < PADSLOTS; i += 256) sorted[i] = -1;
  __syncthreads();
  for (int i = tid; i < NA; i += 256) {
    int e = sel[i];
    int p = atomicAdd(&fill[e], 1);
    sorted[poff_s[e] + p] = i;   // assignment id; token = i>>2
  }
}

// ---------------- convert hidden_states fp32 -> bf16 ----------------
__global__ void cvt_x_kernel(const float* __restrict__ src, u16* __restrict__ dst) {
  int i = (blockIdx.x * 256 + threadIdx.x) * 4;
  float4 v = *(const float4*)&src[i];
  ushort4 o;
  o.x = f2b(v.x); o.y = f2b(v.y); o.z = f2b(v.z); o.w = f2b(v.w);
  *(ushort4*)&dst[i] = o;
}

// ---------------- transpose+convert weights: [E][K][N] fp32 -> [E][N][K] bf16 ----------------
__global__ void transcvt_kernel(const float* __restrict__ src, u16* __restrict__ dst,
                                int K, int N) {
  __shared__ float t[32][33];
  int e = blockIdx.z;
  int n0 = blockIdx.x * 32, k0 = blockIdx.y * 32;
  int tx = threadIdx.x & 31, ty = threadIdx.x >> 5;  // 32 x 8
  const float* s = src + (size_t)e * K * N;
  u16* d = dst + (size_t)e * K * N;
  for (int j = 0; j < 4; ++j)
    t[ty + 8 * j][tx] = s[(size_t)(k0 + ty + 8 * j) * N + n0 + tx];
  __syncthreads();
  for (int j = 0; j < 4; ++j)
    d[(size_t)(n0 + ty + 8 * j) * K + k0 + tx] = f2b(t[tx][ty + 8 * j]);
}

// ---------------- GEMM1: h = silu(x@gate) * (x@up), per expert tile ----------------
// Tile: 128 (M, gathered rows) x 64 (N over I), BK=64, dual accumulators (gate, up).
// 4 waves in 2x2; wave tile 64x32 -> mf=4, nf=2 of 16x16x32 mfma.
__global__ __launch_bounds__(256, 2) void gemm1_kernel(
    const u16* __restrict__ xbf, const u16* __restrict__ gT, const u16* __restrict__ uT,
    u16* __restrict__ hbuf, const int* __restrict__ hdr, const int* __restrict__ sorted) {
  int tile = blockIdx.x;
  if (tile >= hdr[17]) return;
  int e = hdr[32 + tile];
  int slot0 = hdr[80 + tile];
  int n0 = blockIdx.y * 64;
  int tid = threadIdx.x;

  __shared__ u16 sA[128 * 64];   // [m][k]
  __shared__ u16 sBg[64 * 64];   // [n][k]
  __shared__ u16 sBu[64 * 64];

  // staging addresses
  const u16* aptr[4];
  for (int s = 0; s < 4; ++s) {
    int idx = s * 256 + tid;           // 0..1023: row=idx/8, 16B chunk=idx%8
    int row = idx >> 3, kc = idx & 7;
    int as = sorted[slot0 + row];
    int trow = (as >= 0) ? (as >> 2) : 0;
    aptr[s] = xbf + (size_t)trow * NH + kc * 8;
  }
  const u16 *bgp[2], *bup[2];
  for (int s = 0; s < 2; ++s) {
    int idx = s * 256 + tid;           // 0..511: n=idx/8, chunk=idx%8
    int n = idx >> 3, kc = idx & 7;
    size_t o = ((size_t)e * NI + n0 + n) * NH + kc * 8;
    bgp[s] = gT + o; bup[s] = uT + o;
  }

  int lane = tid & 63, wave = tid >> 6;
  int wm = wave >> 1, wn = wave & 1;
  int l15 = lane & 15, quad = lane >> 4;

  f32x4 accg[4][2] = {}; f32x4 accu[4][2] = {};

  for (int kt = 0; kt < NH / 64; ++kt) {
    int ko = kt * 64;
    for (int s = 0; s < 4; ++s) llds16(aptr[s] + ko, &sA[(s * 256 + tid) * 8]);
    for (int s = 0; s < 2; ++s) {
      llds16(bgp[s] + ko, &sBg[(s * 256 + tid) * 8]);
      llds16(bup[s] + ko, &sBu[(s * 256 + tid) * 8]);
    }
    __syncthreads();
    for (int ks = 0; ks < 2; ++ks) {
      short8 av[4], bg[2], bu[2];
      for (int mf = 0; mf < 4; ++mf)
        av[mf] = *(const short8*)&sA[(wm * 64 + mf * 16 + l15) * 64 + ks * 32 + quad * 8];
      for (int nf = 0; nf < 2; ++nf) {
        bg[nf] = *(const short8*)&sBg[(wn * 32 + nf * 16 + l15) * 64 + ks * 32 + quad * 8];
        bu[nf] = *(const short8*)&sBu[(wn * 32 + nf * 16 + l15) * 64 + ks * 32 + quad * 8];
      }
      for (int mf = 0; mf < 4; ++mf)
        for (int nf = 0; nf < 2; ++nf) {
          accg[mf][nf] = __builtin_amdgcn_mfma_f32_16x16x32_bf16(av[mf], bg[nf], accg[mf][nf], 0, 0, 0);
          accu[mf][nf] = __builtin_amdgcn_mfma_f32_16x16x32_bf16(av[mf], bu[nf], accu[mf][nf], 0, 0, 0);
        }
    }
    __syncthreads();
  }

  // epilogue: h = silu(g)*u -> bf16, stored by bucket slot (contiguous for GEMM2)
  for (int mf = 0; mf < 4; ++mf)
    for (int nf = 0; nf < 2; ++nf)
      for (int r = 0; r < 4; ++r) {
        int row = wm * 64 + mf * 16 + quad * 4 + r;
        int col = n0 + wn * 32 + nf * 16 + l15;
        float g = accg[mf][nf][r], u = accu[mf][nf][r];
        float hv = (g / (1.f + __expf(-g))) * u;
        hbuf[(size_t)(slot0 + row) * NI + col] = f2b(hv);
      }
}

// ---------------- GEMM2: down projection, 128x128 tile ----------------
__global__ __launch_bounds__(256, 2) void gemm2_kernel(
    const u16* __restrict__ hbuf, const u16* __restrict__ dT,
    float* __restrict__ dtmp, const int* __restrict__ hdr, const int* __restrict__ sorted) {
  int tile = blockIdx.x;
  if (tile >= hdr[17]) return;
  int e = hdr[32 + tile];
  int slot0 = hdr[80 + tile];
  int n0 = blockIdx.y * 128;
  int tid = threadIdx.x;

  __shared__ u16 sA[128 * 64];   // [m][k]
  __shared__ u16 sB[128 * 64];   // [n][k]

  const u16 *ap[4], *bp[4];
  for (int s = 0; s < 4; ++s) {
    int idx = s * 256 + tid;
    int r = idx >> 3, kc = idx & 7;
    ap[s] = hbuf + (size_t)(slot0 + r) * NI + kc * 8;
    bp[s] = dT + ((size_t)e * NH + n0 + r) * NI + kc * 8;
  }

  int lane = tid & 63, wave = tid >> 6;
  int wm = wave >> 1, wn = wave & 1;
  int l15 = lane & 15, quad = lane >> 4;

  f32x4 acc[4][4] = {};

  for (int kt = 0; kt < NI / 64; ++kt) {
    int ko = kt * 64;
    for (int s = 0; s < 4; ++s) llds16(ap[s] + ko, &sA[(s * 256 + tid) * 8]);
    for (int s = 0; s < 4; ++s) llds16(bp[s] + ko, &sB[(s * 256 + tid) * 8]);
    __syncthreads();
    for (int ks = 0; ks < 2; ++ks) {
      short8 av[4], bv[4];
      for (int mf = 0; mf < 4; ++mf)
        av[mf] = *(const short8*)&sA[(wm * 64 + mf * 16 + l15) * 64 + ks * 32 + quad * 8];
      for (int nf = 0; nf < 4; ++nf)
        bv[nf] = *(const short8*)&sB[(wn * 64 + nf * 16 + l15) * 64 + ks * 32 + quad * 8];
      for (int mf = 0; mf < 4; ++mf)
        for (int nf = 0; nf < 4; ++nf)
          acc[mf][nf] = __builtin_amdgcn_mfma_f32_16x16x32_bf16(av[mf], bv[nf], acc[mf][nf], 0, 0, 0);
    }
    __syncthreads();
  }

  for (int mf = 0; mf < 4; ++mf) {
    int rowb = wm * 64 + mf * 16 + quad * 4;
    for (int r = 0; r < 4; ++r) {
      int as = sorted[slot0 + rowb + r];
      if (as < 0) continue;
      float* orow = dtmp + (size_t)as * NH + n0 + wn * 64;
      for (int nf = 0; nf < 4; ++nf)
        orow[nf * 16 + l15] = acc[mf][nf][r];
    }
  }
}

// ---------------- combine: out[t] = sum_k rw[t,k] * dtmp[t*4+k] ----------------
__global__ void combine_kernel(const float* __restrict__ dtmp, const float* __restrict__ rw,
                               float* __restrict__ out) {
  int t = blockIdx.x;
  int c = threadIdx.x * 4;
  float4 acc = make_float4(0.f, 0.f, 0.f, 0.f);
  for (int k = 0; k < NK; ++k) {
    float w = rw[t * NK + k];
    float4 v = *(const float4*)&dtmp[(size_t)(t * NK + k) * NH + c];
    acc.x += w * v.x; acc.y += w * v.y; acc.z += w * v.z; acc.w += w * v.w;
  }
  *(float4*)&out[(size_t)t * NH + c] = acc;
}

extern "C" void kernel_launch(void* const* d_in, const int* in_sizes, int n_in,
                              void* d_out, int out_size, void* d_ws, size_t ws_size,
                              hipStream_t stream) {
  const float* hs  = (const float*)d_in[0];
  const float* rw  = (const float*)d_in[1];
  const float* gw  = (const float*)d_in[2];
  const float* uw  = (const float*)d_in[3];
  const float* dw  = (const float*)d_in[4];
  const int*   sel = (const int*)d_in[5];
  float* out = (float*)d_out;

  char* ws = (char*)d_ws;
  int*  hdr    = (int*)(ws + WS_HDR);
  int*  sorted = (int*)(ws + WS_SORT);
  u16*  xbf    = (u16*)(ws + WS_XBF);
  u16*  gT     = (u16*)(ws + WS_GT);
  u16*  uT     = (u16*)(ws + WS_UT);
  u16*  dT     = (u16*)(ws + WS_DT);
  u16*  hb     = (u16*)(ws + WS_HB);
  float* dtmp  = (float*)(ws + WS_DTMP);

  hipLaunchKernelGGL(bucket_kernel, dim3(1), dim3(256), 0, stream, sel, hdr, sorted);
  hipLaunchKernelGGL(cvt_x_kernel, dim3(NT * NH / 1024), dim3(256), 0, stream, hs, xbf);
  // gate/up: K=NH rows, N=NI cols -> [E][NI][NH]
  hipLaunchKernelGGL(transcvt_kernel, dim3(NI / 32, NH / 32, NE), dim3(256), 0, stream, gw, gT, NH, NI);
  hipLaunchKernelGGL(transcvt_kernel, dim3(NI / 32, NH / 32, NE), dim3(256), 0, stream, uw, uT, NH, NI);
  // down: K=NI rows, N=NH cols -> [E][NH][NI]
  hipLaunchKernelGGL(transcvt_kernel, dim3(NH / 32, NI / 32, NE), dim3(256), 0, stream, dw, dT, NI, NH);
  hipLaunchKernelGGL(gemm1_kernel, dim3(MAXTILES, NI / 64), dim3(256), 0, stream, xbf, gT, uT, hb, hdr, sorted);
  hipLaunchKernelGGL(gemm2_kernel, dim3(MAXTILES, NH / 128), dim3(256), 0, stream, hb, dT, dtmp, hdr, sorted);
  hipLaunchKernelGGL(combine_kernel, dim3(NT), dim3(256), 0, stream, dtmp, rw, out);
}

// Round 2
// 261.015 us; speedup vs baseline: 1.0833x; 1.0833x over previous
//
#include <hip/hip_runtime.h>
#include <hip/hip_bf16.h>
#include <cstdint>
#include <cstddef>

// Problem constants (DeepseekV3Experts: T=1024 H=1024 I=1408 E=8 K=4)
#define NE 8
#define NT 1024
#define NK 4
#define NH 1024
#define NI 1408
#define NA (NT * NK)      // 4096 assignments
#define BM 128            // row tile
#define MAXTILES 40
#define PADSLOTS 5120

typedef short short8 __attribute__((ext_vector_type(8)));
typedef float f32x4 __attribute__((ext_vector_type(4)));
typedef unsigned short u16;

// Workspace layout (bytes). Total ~97.8 MB.
#define WS_HDR   0
#define WS_SORT  1024
#define WS_XBF   21504      // u16[NT*NH]
#define WS_GT    2118656    // u16[NE*NI*NH]  gate^T [E][I][H]
#define WS_UT    25187328   // u16[NE*NI*NH]  up^T
#define WS_DT    48256000   // u16[NE*NH*NI]  down^T [E][H][I]
#define WS_HB    71324672   // u16[PADSLOTS*NI]
#define WS_DTMP  85742592   // float[NA*NH]

__device__ __forceinline__ u16 f2b(float f) {
  union { float f; uint32_t u; } c; c.f = f;
  uint32_t u = c.u;
  return (u16)((u + 0x7FFFu + ((u >> 16) & 1u)) >> 16);  // RNE
}

__device__ __forceinline__ void llds16(const void* g, void* l) {
  __builtin_amdgcn_global_load_lds(
      (const __attribute__((address_space(1))) void*)g,
      (__attribute__((address_space(3))) void*)l, 16, 0, 0);
}

// ---------------- bucket ----------------
__global__ void bucket_kernel(const int* __restrict__ sel, int* __restrict__ hdr,
                              int* __restrict__ sorted) {
  __shared__ int cnt[NE], fill[NE], poff_s[NE + 1];
  int tid = threadIdx.x;
  if (tid < NE) { cnt[tid] = 0; fill[tid] = 0; }
  __syncthreads();
  for (int i = tid; i < NA; i += 256) atomicAdd(&cnt[sel[i]], 1);
  __syncthreads();
  if (tid == 0) {
    int off = 0, nt = 0;
    for (int e = 0; e < NE; ++e) {
      poff_s[e] = off;
      int tiles = (cnt[e] + BM - 1) / BM;
      for (int j = 0; j < tiles; ++j) { hdr[32 + nt] = e; hdr[80 + nt] = off + j * BM; ++nt; }
      off += tiles * BM;
    }
    poff_s[NE] = off;
    hdr[17] = nt;
    for (int e = 0; e < NE; ++e) hdr[e] = cnt[e];
    for (int e = 0; e <= NE; ++e) hdr[8 + e] = poff_s[e];
  }
  __syncthreads();
  for (int i = tid; i < PADSLOTS; i += 256) sorted[i] = -1;
  __syncthreads();
  for (int i = tid; i < NA; i += 256) {
    int e = sel[i];
    int p = atomicAdd(&fill[e], 1);
    sorted[poff_s[e] + p] = i;
  }
}

// ---------------- convert hidden_states fp32 -> bf16 ----------------
__global__ void cvt_x_kernel(const float* __restrict__ src, u16* __restrict__ dst) {
  int i = (blockIdx.x * 256 + threadIdx.x) * 4;
  float4 v = *(const float4*)&src[i];
  ushort4 o;
  o.x = f2b(v.x); o.y = f2b(v.y); o.z = f2b(v.z); o.w = f2b(v.w);
  *(ushort4*)&dst[i] = o;
}

// ---------------- fused transpose+convert for all 3 weight tensors ----------------
// [E][K][N] fp32 -> [E][N][K] bf16. Grid (22, 16, 24); z: tensor=z>>3, e=z&7.
// gate/up: K=1024,N=1408 (nb=bx 22, kb=by 16); down: K=1408,N=1024 (kb=bx, nb=by).
__global__ __launch_bounds__(256) void transcvt_all(
    const float* __restrict__ gw, const float* __restrict__ uw, const float* __restrict__ dw,
    u16* __restrict__ gT, u16* __restrict__ uT, u16* __restrict__ dT) {
  __shared__ float t[64][65];
  int z = blockIdx.z;
  int tensor = z >> 3, e = z & 7;
  const float* src; u16* dst; int K, N, kb, nb;
  if (tensor == 0)      { src = gw; dst = gT; }
  else if (tensor == 1) { src = uw; dst = uT; }
  else                  { src = dw; dst = dT; }
  if (tensor < 2) { K = NH; N = NI; nb = blockIdx.x; kb = blockIdx.y; }
  else            { K = NI; N = NH; kb = blockIdx.x; nb = blockIdx.y; }
  int k0 = kb * 64, n0 = nb * 64;
  src += (size_t)e * K * N;
  dst += (size_t)e * K * N;
  int tid = threadIdx.x;
  for (int i = 0; i < 4; ++i) {
    int idx = i * 256 + tid;
    int r = idx >> 4, c = idx & 15;
    *(float4*)&t[r][c * 4] = *(const float4*)&src[(size_t)(k0 + r) * N + n0 + c * 4];
  }
  __syncthreads();
  for (int i = 0; i < 2; ++i) {
    int idx = i * 256 + tid;
    int n = idx >> 3, kc = idx & 7;
    u16 o[8];
#pragma unroll
    for (int j = 0; j < 8; ++j) o[j] = f2b(t[kc * 8 + j][n]);
    *(short8*)&dst[(size_t)(n0 + n) * K + k0 + kc * 8] = *(const short8*)o;
  }
}

// ---------------- GEMM1: h = silu(x@gate) * (x@up) ----------------
// 128(M) x 64(N over I), BK=64, dual acc. XOR-swizzled LDS: 16B chunk kc of row r
// lives at position kc ^ (r&7) -> fragment reads spread over all 32 banks (2-way max).
__global__ __launch_bounds__(256, 2) void gemm1_kernel(
    const u16* __restrict__ xbf, const u16* __restrict__ gT, const u16* __restrict__ uT,
    u16* __restrict__ hbuf, const int* __restrict__ hdr, const int* __restrict__ sorted) {
  int tile = blockIdx.x;
  if (tile >= hdr[17]) return;
  int e = hdr[32 + tile];
  int slot0 = hdr[80 + tile];
  int n0 = blockIdx.y * 64;
  int tid = threadIdx.x;

  __shared__ u16 sA[128 * 64];   // [m][k], swizzled
  __shared__ u16 sBg[64 * 64];   // [n][k], swizzled
  __shared__ u16 sBu[64 * 64];

  const u16* aptr[4];
  for (int s = 0; s < 4; ++s) {
    int idx = s * 256 + tid;
    int row = idx >> 3, c = idx & 7;
    int kc = c ^ (row & 7);                    // swizzle: pos c holds chunk kc
    int as = sorted[slot0 + row];
    int trow = (as >= 0) ? (as >> 2) : 0;
    aptr[s] = xbf + (size_t)trow * NH + kc * 8;
  }
  const u16 *bgp[2], *bup[2];
  for (int s = 0; s < 2; ++s) {
    int idx = s * 256 + tid;
    int n = idx >> 3, c = idx & 7;
    int kc = c ^ (n & 7);
    size_t o = ((size_t)e * NI + n0 + n) * NH + kc * 8;
    bgp[s] = gT + o; bup[s] = uT + o;
  }

  int lane = tid & 63, wave = tid >> 6;
  int wm = wave >> 1, wn = wave & 1;
  int l15 = lane & 15, quad = lane >> 4;
  int sw = l15 & 7;                            // row&7 for all fragment rows

  f32x4 accg[4][2] = {}; f32x4 accu[4][2] = {};

  for (int kt = 0; kt < NH / 64; ++kt) {
    int ko = kt * 64;
    for (int s = 0; s < 4; ++s) llds16(aptr[s] + ko, &sA[(s * 256 + tid) * 8]);
    for (int s = 0; s < 2; ++s) {
      llds16(bgp[s] + ko, &sBg[(s * 256 + tid) * 8]);
      llds16(bup[s] + ko, &sBu[(s * 256 + tid) * 8]);
    }
    __syncthreads();
    for (int ks = 0; ks < 2; ++ks) {
      int pos = ((ks * 4 + quad) ^ sw) * 8;    // swizzled k-chunk position
      short8 av[4], bg[2], bu[2];
      for (int mf = 0; mf < 4; ++mf)
        av[mf] = *(const short8*)&sA[(wm * 64 + mf * 16 + l15) * 64 + pos];
      for (int nf = 0; nf < 2; ++nf) {
        bg[nf] = *(const short8*)&sBg[(wn * 32 + nf * 16 + l15) * 64 + pos];
        bu[nf] = *(const short8*)&sBu[(wn * 32 + nf * 16 + l15) * 64 + pos];
      }
      for (int mf = 0; mf < 4; ++mf)
        for (int nf = 0; nf < 2; ++nf) {
          accg[mf][nf] = __builtin_amdgcn_mfma_f32_16x16x32_bf16(av[mf], bg[nf], accg[mf][nf], 0, 0, 0);
          accu[mf][nf] = __builtin_amdgcn_mfma_f32_16x16x32_bf16(av[mf], bu[nf], accu[mf][nf], 0, 0, 0);
        }
    }
    __syncthreads();
  }

  for (int mf = 0; mf < 4; ++mf)
    for (int nf = 0; nf < 2; ++nf)
      for (int r = 0; r < 4; ++r) {
        int row = wm * 64 + mf * 16 + quad * 4 + r;
        int col = n0 + wn * 32 + nf * 16 + l15;
        float g = accg[mf][nf][r], u = accu[mf][nf][r];
        float hv = (g / (1.f + __expf(-g))) * u;
        hbuf[(size_t)(slot0 + row) * NI + col] = f2b(hv);
      }
}

// ---------------- GEMM2: down projection, 128x128 ----------------
__global__ __launch_bounds__(256, 2) void gemm2_kernel(
    const u16* __restrict__ hbuf, const u16* __restrict__ dT,
    float* __restrict__ dtmp, const int* __restrict__ hdr, const int* __restrict__ sorted) {
  int tile = blockIdx.x;
  if (tile >= hdr[17]) return;
  int e = hdr[32 + tile];
  int slot0 = hdr[80 + tile];
  int n0 = blockIdx.y * 128;
  int tid = threadIdx.x;

  __shared__ u16 sA[128 * 64];   // [m][k], swizzled
  __shared__ u16 sB[128 * 64];   // [n][k], swizzled

  const u16 *ap[4], *bp[4];
  for (int s = 0; s < 4; ++s) {
    int idx = s * 256 + tid;
    int r = idx >> 3, c = idx & 7;
    int kc = c ^ (r & 7);
    ap[s] = hbuf + (size_t)(slot0 + r) * NI + kc * 8;
    bp[s] = dT + ((size_t)e * NH + n0 + r) * NI + kc * 8;
  }

  int lane = tid & 63, wave = tid >> 6;
  int wm = wave >> 1, wn = wave & 1;
  int l15 = lane & 15, quad = lane >> 4;
  int sw = l15 & 7;

  f32x4 acc[4][4] = {};

  for (int kt = 0; kt < NI / 64; ++kt) {
    int ko = kt * 64;
    for (int s = 0; s < 4; ++s) llds16(ap[s] + ko, &sA[(s * 256 + tid) * 8]);
    for (int s = 0; s < 4; ++s) llds16(bp[s] + ko, &sB[(s * 256 + tid) * 8]);
    __syncthreads();
    for (int ks = 0; ks < 2; ++ks) {
      int pos = ((ks * 4 + quad) ^ sw) * 8;
      short8 av[4], bv[4];
      for (int mf = 0; mf < 4; ++mf)
        av[mf] = *(const short8*)&sA[(wm * 64 + mf * 16 + l15) * 64 + pos];
      for (int nf = 0; nf < 4; ++nf)
        bv[nf] = *(const short8*)&sB[(wn * 64 + nf * 16 + l15) * 64 + pos];
      for (int mf = 0; mf < 4; ++mf)
        for (int nf = 0; nf < 4; ++nf)
          acc[mf][nf] = __builtin_amdgcn_mfma_f32_16x16x32_bf16(av[mf], bv[nf], acc[mf][nf], 0, 0, 0);
    }
    __syncthreads();
  }

  for (int mf = 0; mf < 4; ++mf) {
    int rowb = wm * 64 + mf * 16 + quad * 4;
    for (int r = 0; r < 4; ++r) {
      int as = sorted[slot0 + rowb + r];
      if (as < 0) continue;
      float* orow = dtmp + (size_t)as * NH + n0 + wn * 64;
      for (int nf = 0; nf < 4; ++nf)
        orow[nf * 16 + l15] = acc[mf][nf][r];
    }
  }
}

// ---------------- combine ----------------
__global__ void combine_kernel(const float* __restrict__ dtmp, const float* __restrict__ rw,
                               float* __restrict__ out) {
  int t = blockIdx.x;
  int c = threadIdx.x * 4;
  float4 acc = make_float4(0.f, 0.f, 0.f, 0.f);
  for (int k = 0; k < NK; ++k) {
    float w = rw[t * NK + k];
    float4 v = *(const float4*)&dtmp[(size_t)(t * NK + k) * NH + c];
    acc.x += w * v.x; acc.y += w * v.y; acc.z += w * v.z; acc.w += w * v.w;
  }
  *(float4*)&out[(size_t)t * NH + c] = acc;
}

extern "C" void kernel_launch(void* const* d_in, const int* in_sizes, int n_in,
                              void* d_out, int out_size, void* d_ws, size_t ws_size,
                              hipStream_t stream) {
  const float* hs  = (const float*)d_in[0];
  const float* rw  = (const float*)d_in[1];
  const float* gw  = (const float*)d_in[2];
  const float* uw  = (const float*)d_in[3];
  const float* dw  = (const float*)d_in[4];
  const int*   sel = (const int*)d_in[5];
  float* out = (float*)d_out;

  char* ws = (char*)d_ws;
  int*  hdr    = (int*)(ws + WS_HDR);
  int*  sorted = (int*)(ws + WS_SORT);
  u16*  xbf    = (u16*)(ws + WS_XBF);
  u16*  gT     = (u16*)(ws + WS_GT);
  u16*  uT     = (u16*)(ws + WS_UT);
  u16*  dT     = (u16*)(ws + WS_DT);
  u16*  hb     = (u16*)(ws + WS_HB);
  float* dtmp  = (float*)(ws + WS_DTMP);

  hipLaunchKernelGGL(bucket_kernel, dim3(1), dim3(256), 0, stream, sel, hdr, sorted);
  hipLaunchKernelGGL(cvt_x_kernel, dim3(NT * NH / 1024), dim3(256), 0, stream, hs, xbf);
  hipLaunchKernelGGL(transcvt_all, dim3(22, 16, 24), dim3(256), 0, stream, gw, uw, dw, gT, uT, dT);
  hipLaunchKernelGGL(gemm1_kernel, dim3(MAXTILES, NI / 64), dim3(256), 0, stream, xbf, gT, uT, hb, hdr, sorted);
  hipLaunchKernelGGL(gemm2_kernel, dim3(MAXTILES, NH / 128), dim3(256), 0, stream, hb, dT, dtmp, hdr, sorted);
  hipLaunchKernelGGL(combine_kernel, dim3(NT), dim3(256), 0, stream, dtmp, rw, out);
}

// Round 4
// 248.518 us; speedup vs baseline: 1.1378x; 1.0503x over previous
//
#include <hip/hip_runtime.h>
#include <hip/hip_bf16.h>
#include <cstdint>
#include <cstddef>

// Problem constants (DeepseekV3Experts: T=1024 H=1024 I=1408 E=8 K=4)
#define NE 8
#define NT 1024
#define NK 4
#define NH 1024
#define NI 1408
#define NA (NT * NK)      // 4096 assignments
#define BM 128            // row tile
#define MAXTILES 40
#define PADSLOTS 5120

typedef short short8 __attribute__((ext_vector_type(8)));
typedef float f32x4 __attribute__((ext_vector_type(4)));
typedef float f4v __attribute__((ext_vector_type(4)));   // clang-native for nontemporal builtins
typedef unsigned short u16;

// Workspace layout (bytes). Total ~97.8 MB.
#define WS_HDR   0
#define WS_SORT  1024
#define WS_XBF   21504      // u16[NT*NH]
#define WS_GT    2118656    // u16[NE*NI*NH]  gate^T [E][I][H]
#define WS_UT    25187328   // u16[NE*NI*NH]  up^T
#define WS_DT    48256000   // u16[NE*NH*NI]  down^T [E][H][I]
#define WS_HB    71324672   // u16[PADSLOTS*NI]
#define WS_DTMP  85742592   // float[NA*NH]

__device__ __forceinline__ u16 f2b(float f) {
  union { float f; uint32_t u; } c; c.f = f;
  uint32_t u = c.u;
  return (u16)((u + 0x7FFFu + ((u >> 16) & 1u)) >> 16);  // RNE
}

__device__ __forceinline__ void llds16(const void* g, void* l) {
  __builtin_amdgcn_global_load_lds(
      (const __attribute__((address_space(1))) void*)g,
      (__attribute__((address_space(3))) void*)l, 16, 0, 0);
}

// ---------------- bucket ----------------
__global__ void bucket_kernel(const int* __restrict__ sel, int* __restrict__ hdr,
                              int* __restrict__ sorted) {
  __shared__ int cnt[NE], fill[NE], poff_s[NE + 1];
  int tid = threadIdx.x;
  if (tid < NE) { cnt[tid] = 0; fill[tid] = 0; }
  __syncthreads();
  for (int i = tid; i < NA; i += 256) atomicAdd(&cnt[sel[i]], 1);
  __syncthreads();
  if (tid == 0) {
    int off = 0, nt = 0;
    for (int e = 0; e < NE; ++e) {
      poff_s[e] = off;
      int tiles = (cnt[e] + BM - 1) / BM;
      for (int j = 0; j < tiles; ++j) { hdr[32 + nt] = e; hdr[80 + nt] = off + j * BM; ++nt; }
      off += tiles * BM;
    }
    poff_s[NE] = off;
    hdr[17] = nt;
    for (int e = 0; e < NE; ++e) hdr[e] = cnt[e];
    for (int e = 0; e <= NE; ++e) hdr[8 + e] = poff_s[e];
  }
  __syncthreads();
  for (int i = tid; i < PADSLOTS; i += 256) sorted[i] = -1;
  __syncthreads();
  for (int i = tid; i < NA; i += 256) {
    int e = sel[i];
    int p = atomicAdd(&fill[e], 1);
    sorted[poff_s[e] + p] = i;
  }
}

// ---------------- fused convert/transpose for all weights + hidden_states ----------------
// Weights: [E][K][N] fp32 -> [E][N][K] bf16, 64k x 128n stripe per block, bf16-in-LDS.
// Grid (176, 25): y<24 -> tensor=y>>3, e=y&7; y==24 -> x fp32->bf16 passthrough.
// gate/up: K=1024,N=1408 -> 11 n-stripes x 16 k-blocks = 176. down: K=1408,N=1024 -> 8 x 22 = 176.
__global__ __launch_bounds__(256) void transcvt_all(
    const float* __restrict__ gw, const float* __restrict__ uw, const float* __restrict__ dw,
    const float* __restrict__ hs,
    u16* __restrict__ gT, u16* __restrict__ uT, u16* __restrict__ dT, u16* __restrict__ xbf) {
  int tid = threadIdx.x;
  int y = blockIdx.y;
  if (y == 24) {  // hidden_states convert (1M elements)
    for (int i = blockIdx.x * 256 + tid; i * 4 < NT * NH; i += 176 * 256) {
      f4v v = __builtin_nontemporal_load((const f4v*)&hs[i * 4]);
      ushort4 o;
      o.x = f2b(v.x); o.y = f2b(v.y); o.z = f2b(v.z); o.w = f2b(v.w);
      *(ushort4*)&xbf[i * 4] = o;
    }
    return;
  }
  __shared__ u16 t2[2][64][72];
  int tensor = y >> 3, e = y & 7;
  const float* src; u16* dst; int K, N, kb, nb;
  if (tensor == 0)      { src = gw; dst = gT; }
  else if (tensor == 1) { src = uw; dst = uT; }
  else                  { src = dw; dst = dT; }
  if (tensor < 2) { K = NH; N = NI; nb = blockIdx.x % 11; kb = blockIdx.x / 11; }
  else            { K = NI; N = NH; nb = blockIdx.x % 8;  kb = blockIdx.x / 8;  }
  int k0 = kb * 64, n0 = nb * 128;
  src += (size_t)e * K * N;
  dst += (size_t)e * K * N;

  int r = tid >> 4, c = tid & 15;          // 16 x 16 over (row, col16)
  // issue ALL global loads up front (128 B/thread outstanding)
  f4v v[2][4];
#pragma unroll
  for (int t = 0; t < 2; ++t)
#pragma unroll
    for (int i = 0; i < 4; ++i)
      v[t][i] = __builtin_nontemporal_load(
          (const f4v*)&src[(size_t)(k0 + r + 16 * i) * N + n0 + t * 64 + c * 4]);
#pragma unroll
  for (int t = 0; t < 2; ++t)
#pragma unroll
    for (int i = 0; i < 4; ++i) {
      ushort4 o;
      o.x = f2b(v[t][i].x); o.y = f2b(v[t][i].y); o.z = f2b(v[t][i].z); o.w = f2b(v[t][i].w);
      *(ushort4*)&t2[t][r + 16 * i][c * 4] = o;
    }
  __syncthreads();
#pragma unroll
  for (int t = 0; t < 2; ++t)
#pragma unroll
    for (int i = 0; i < 2; ++i) {
      int idx = i * 256 + tid;
      int n = idx >> 3, kc = idx & 7;
      u16 o[8];
#pragma unroll
      for (int j = 0; j < 8; ++j) o[j] = t2[t][kc * 8 + j][n];
      *(short8*)&dst[(size_t)(n0 + t * 64 + n) * K + k0 + kc * 8] = *(const short8*)o;
    }
}

// ---------------- GEMM1: h = silu(x@gate) * (x@up) ----------------
// 128(M) x 64(N over I), BK=64, dual acc, XOR-swizzled LDS.
__global__ __launch_bounds__(256, 4) void gemm1_kernel(
    const u16* __restrict__ xbf, const u16* __restrict__ gT, const u16* __restrict__ uT,
    u16* __restrict__ hbuf, const int* __restrict__ hdr, const int* __restrict__ sorted) {
  int tile = blockIdx.x;
  if (tile >= hdr[17]) return;
  int e = hdr[32 + tile];
  int slot0 = hdr[80 + tile];
  int n0 = blockIdx.y * 64;
  int tid = threadIdx.x;

  __shared__ u16 sA[128 * 64];   // [m][k], swizzled
  __shared__ u16 sBg[64 * 64];   // [n][k], swizzled
  __shared__ u16 sBu[64 * 64];

  const u16* aptr[4];
  for (int s = 0; s < 4; ++s) {
    int idx = s * 256 + tid;
    int row = idx >> 3, c = idx & 7;
    int kc = c ^ (row & 7);
    int as = sorted[slot0 + row];
    int trow = (as >= 0) ? (as >> 2) : 0;
    aptr[s] = xbf + (size_t)trow * NH + kc * 8;
  }
  const u16 *bgp[2], *bup[2];
  for (int s = 0; s < 2; ++s) {
    int idx = s * 256 + tid;
    int n = idx >> 3, c = idx & 7;
    int kc = c ^ (n & 7);
    size_t o = ((size_t)e * NI + n0 + n) * NH + kc * 8;
    bgp[s] = gT + o; bup[s] = uT + o;
  }

  int lane = tid & 63, wave = tid >> 6;
  int wm = wave >> 1, wn = wave & 1;
  int l15 = lane & 15, quad = lane >> 4;
  int sw = l15 & 7;

  f32x4 accg[4][2] = {}; f32x4 accu[4][2] = {};

  for (int kt = 0; kt < NH / 64; ++kt) {
    int ko = kt * 64;
    for (int s = 0; s < 4; ++s) llds16(aptr[s] + ko, &sA[(s * 256 + tid) * 8]);
    for (int s = 0; s < 2; ++s) {
      llds16(bgp[s] + ko, &sBg[(s * 256 + tid) * 8]);
      llds16(bup[s] + ko, &sBu[(s * 256 + tid) * 8]);
    }
    __syncthreads();
    for (int ks = 0; ks < 2; ++ks) {
      int pos = ((ks * 4 + quad) ^ sw) * 8;
      short8 av[4], bg[2], bu[2];
      for (int mf = 0; mf < 4; ++mf)
        av[mf] = *(const short8*)&sA[(wm * 64 + mf * 16 + l15) * 64 + pos];
      for (int nf = 0; nf < 2; ++nf) {
        bg[nf] = *(const short8*)&sBg[(wn * 32 + nf * 16 + l15) * 64 + pos];
        bu[nf] = *(const short8*)&sBu[(wn * 32 + nf * 16 + l15) * 64 + pos];
      }
      for (int mf = 0; mf < 4; ++mf)
        for (int nf = 0; nf < 2; ++nf) {
          accg[mf][nf] = __builtin_amdgcn_mfma_f32_16x16x32_bf16(av[mf], bg[nf], accg[mf][nf], 0, 0, 0);
          accu[mf][nf] = __builtin_amdgcn_mfma_f32_16x16x32_bf16(av[mf], bu[nf], accu[mf][nf], 0, 0, 0);
        }
    }
    __syncthreads();
  }

  for (int mf = 0; mf < 4; ++mf)
    for (int nf = 0; nf < 2; ++nf)
      for (int r = 0; r < 4; ++r) {
        int row = wm * 64 + mf * 16 + quad * 4 + r;
        int col = n0 + wn * 32 + nf * 16 + l15;
        float g = accg[mf][nf][r], u = accu[mf][nf][r];
        float hv = (g / (1.f + __expf(-g))) * u;
        hbuf[(size_t)(slot0 + row) * NI + col] = f2b(hv);
      }
}

// ---------------- GEMM2: down projection, 128x128 ----------------
__global__ __launch_bounds__(256, 4) void gemm2_kernel(
    const u16* __restrict__ hbuf, const u16* __restrict__ dT,
    float* __restrict__ dtmp, const int* __restrict__ hdr, const int* __restrict__ sorted) {
  int tile = blockIdx.x;
  if (tile >= hdr[17]) return;
  int e = hdr[32 + tile];
  int slot0 = hdr[80 + tile];
  int n0 = blockIdx.y * 128;
  int tid = threadIdx.x;

  __shared__ u16 sA[128 * 64];   // [m][k], swizzled
  __shared__ u16 sB[128 * 64];   // [n][k], swizzled

  const u16 *ap[4], *bp[4];
  for (int s = 0; s < 4; ++s) {
    int idx = s * 256 + tid;
    int r = idx >> 3, c = idx & 7;
    int kc = c ^ (r & 7);
    ap[s] = hbuf + (size_t)(slot0 + r) * NI + kc * 8;
    bp[s] = dT + ((size_t)e * NH + n0 + r) * NI + kc * 8;
  }

  int lane = tid & 63, wave = tid >> 6;
  int wm = wave >> 1, wn = wave & 1;
  int l15 = lane & 15, quad = lane >> 4;
  int sw = l15 & 7;

  f32x4 acc[4][4] = {};

  for (int kt = 0; kt < NI / 64; ++kt) {
    int ko = kt * 64;
    for (int s = 0; s < 4; ++s) llds16(ap[s] + ko, &sA[(s * 256 + tid) * 8]);
    for (int s = 0; s < 4; ++s) llds16(bp[s] + ko, &sB[(s * 256 + tid) * 8]);
    __syncthreads();
    for (int ks = 0; ks < 2; ++ks) {
      int pos = ((ks * 4 + quad) ^ sw) * 8;
      short8 av[4], bv[4];
      for (int mf = 0; mf < 4; ++mf)
        av[mf] = *(const short8*)&sA[(wm * 64 + mf * 16 + l15) * 64 + pos];
      for (int nf = 0; nf < 4; ++nf)
        bv[nf] = *(const short8*)&sB[(wn * 64 + nf * 16 + l15) * 64 + pos];
      for (int mf = 0; mf < 4; ++mf)
        for (int nf = 0; nf < 4; ++nf)
          acc[mf][nf] = __builtin_amdgcn_mfma_f32_16x16x32_bf16(av[mf], bv[nf], acc[mf][nf], 0, 0, 0);
    }
    __syncthreads();
  }

  for (int mf = 0; mf < 4; ++mf) {
    int rowb = wm * 64 + mf * 16 + quad * 4;
    for (int r = 0; r < 4; ++r) {
      int as = sorted[slot0 + rowb + r];
      if (as < 0) continue;
      float* orow = dtmp + (size_t)as * NH + n0 + wn * 64;
      for (int nf = 0; nf < 4; ++nf)
        orow[nf * 16 + l15] = acc[mf][nf][r];
    }
  }
}

// ---------------- combine ----------------
__global__ void combine_kernel(const float* __restrict__ dtmp, const float* __restrict__ rw,
                               float* __restrict__ out) {
  int t = blockIdx.x;
  int c = threadIdx.x * 4;
  float4 acc = make_float4(0.f, 0.f, 0.f, 0.f);
  for (int k = 0; k < NK; ++k) {
    float w = rw[t * NK + k];
    float4 v = *(const float4*)&dtmp[(size_t)(t * NK + k) * NH + c];
    acc.x += w * v.x; acc.y += w * v.y; acc.z += w * v.z; acc.w += w * v.w;
  }
  *(float4*)&out[(size_t)t * NH + c] = acc;
}

extern "C" void kernel_launch(void* const* d_in, const int* in_sizes, int n_in,
                              void* d_out, int out_size, void* d_ws, size_t ws_size,
                              hipStream_t stream) {
  const float* hs  = (const float*)d_in[0];
  const float* rw  = (const float*)d_in[1];
  const float* gw  = (const float*)d_in[2];
  const float* uw  = (const float*)d_in[3];
  const float* dw  = (const float*)d_in[4];
  const int*   sel = (const int*)d_in[5];
  float* out = (float*)d_out;

  char* ws = (char*)d_ws;
  int*  hdr    = (int*)(ws + WS_HDR);
  int*  sorted = (int*)(ws + WS_SORT);
  u16*  xbf    = (u16*)(ws + WS_XBF);
  u16*  gT     = (u16*)(ws + WS_GT);
  u16*  uT     = (u16*)(ws + WS_UT);
  u16*  dT     = (u16*)(ws + WS_DT);
  u16*  hb     = (u16*)(ws + WS_HB);
  float* dtmp  = (float*)(ws + WS_DTMP);

  hipLaunchKernelGGL(bucket_kernel, dim3(1), dim3(256), 0, stream, sel, hdr, sorted);
  hipLaunchKernelGGL(transcvt_all, dim3(176, 25), dim3(256), 0, stream,
                     gw, uw, dw, hs, gT, uT, dT, xbf);
  hipLaunchKernelGGL(gemm1_kernel, dim3(MAXTILES, NI / 64), dim3(256), 0, stream, xbf, gT, uT, hb, hdr, sorted);
  hipLaunchKernelGGL(gemm2_kernel, dim3(MAXTILES, NH / 128), dim3(256), 0, stream, hb, dT, dtmp, hdr, sorted);
  hipLaunchKernelGGL(combine_kernel, dim3(NT), dim3(256), 0, stream, dtmp, rw, out);
}

// Round 5
// 247.759 us; speedup vs baseline: 1.1413x; 1.0031x over previous
//
#include <hip/hip_runtime.h>
#include <hip/hip_bf16.h>
#include <cstdint>
#include <cstddef>

// Problem constants (DeepseekV3Experts: T=1024 H=1024 I=1408 E=8 K=4)
#define NE 8
#define NT 1024
#define NK 4
#define NH 1024
#define NI 1408
#define NA (NT * NK)      // 4096 assignments
#define BM 128            // row tile
#define MAXTILES 40
#define PADSLOTS 5120

typedef short short8 __attribute__((ext_vector_type(8)));
typedef float f32x4 __attribute__((ext_vector_type(4)));
typedef float f4v __attribute__((ext_vector_type(4)));   // clang-native for nontemporal builtins
typedef unsigned short u16;

// Workspace layout (bytes).
#define WS_HDR   0
#define WS_SORT  1024
#define WS_XBF   21504      // u16[NT*NH]
#define WS_GT    2118656    // u16[NE*NI*NH]  gate^T [E][I][H]
#define WS_UT    25187328   // u16[NE*NI*NH]  up^T
#define WS_DT    48256000   // u16[NE*NH*NI]  down^T [E][H][I]
#define WS_HB    71324672   // u16[PADSLOTS*NI]

__device__ __forceinline__ u16 f2b(float f) {
  union { float f; uint32_t u; } c; c.f = f;
  uint32_t u = c.u;
  return (u16)((u + 0x7FFFu + ((u >> 16) & 1u)) >> 16);  // RNE
}

__device__ __forceinline__ void llds16(const void* g, void* l) {
  __builtin_amdgcn_global_load_lds(
      (const __attribute__((address_space(1))) void*)g,
      (__attribute__((address_space(3))) void*)l, 16, 0, 0);
}

// Shared transpose-convert stripe: [K][N] fp32 -> [N][K] bf16, 64k x 128n per block.
// smem must hold 2*64*72 u16.
__device__ __forceinline__ void transcvt_stripe(const float* __restrict__ src,
                                                u16* __restrict__ dst,
                                                int K, int N, int k0, int n0,
                                                u16* smem, int tid) {
  u16 (*t2)[64][72] = (u16(*)[64][72])smem;
  int r = tid >> 4, c = tid & 15;          // 16 x 16 over (row, col16)
  f4v v[2][4];
#pragma unroll
  for (int t = 0; t < 2; ++t)
#pragma unroll
    for (int i = 0; i < 4; ++i)
      v[t][i] = __builtin_nontemporal_load(
          (const f4v*)&src[(size_t)(k0 + r + 16 * i) * N + n0 + t * 64 + c * 4]);
#pragma unroll
  for (int t = 0; t < 2; ++t)
#pragma unroll
    for (int i = 0; i < 4; ++i) {
      ushort4 o;
      o.x = f2b(v[t][i].x); o.y = f2b(v[t][i].y); o.z = f2b(v[t][i].z); o.w = f2b(v[t][i].w);
      *(ushort4*)&t2[t][r + 16 * i][c * 4] = o;
    }
  __syncthreads();
#pragma unroll
  for (int t = 0; t < 2; ++t)
#pragma unroll
    for (int i = 0; i < 2; ++i) {
      int idx = i * 256 + tid;
      int n = idx >> 3, kc = idx & 7;
      u16 o[8];
#pragma unroll
      for (int j = 0; j < 8; ++j) o[j] = t2[t][kc * 8 + j][n];
      *(short8*)&dst[(size_t)(n0 + t * 64 + n) * K + k0 + kc * 8] = *(const short8*)o;
    }
}

// ---------------- K1: bucket + gate/up transpose-convert + x convert ----------------
// Grid (176, 18): y<16 -> tensor=y>>3 (0 gate, 1 up), e=y&7, stripe=x (11 nb x 16 kb);
// y==16 -> x convert; y==17 && x==0 -> bucket.
__global__ __launch_bounds__(256) void k1_prep(
    const float* __restrict__ gw, const float* __restrict__ uw, const float* __restrict__ hs,
    const int* __restrict__ sel,
    u16* __restrict__ gT, u16* __restrict__ uT, u16* __restrict__ xbf,
    int* __restrict__ hdr, int* __restrict__ sorted) {
  int tid = threadIdx.x;
  int y = blockIdx.y;
  if (y == 16) {  // hidden_states convert (1M elements)
    for (int i = blockIdx.x * 256 + tid; i * 4 < NT * NH; i += 176 * 256) {
      f4v v = __builtin_nontemporal_load((const f4v*)&hs[i * 4]);
      ushort4 o;
      o.x = f2b(v.x); o.y = f2b(v.y); o.z = f2b(v.z); o.w = f2b(v.w);
      *(ushort4*)&xbf[i * 4] = o;
    }
    return;
  }
  if (y == 17) {  // bucket (single block)
    if (blockIdx.x != 0) return;
    __shared__ int cnt[NE], fill[NE], poff_s[NE + 1];
    if (tid < NE) { cnt[tid] = 0; fill[tid] = 0; }
    __syncthreads();
    for (int i = tid; i < NA; i += 256) atomicAdd(&cnt[sel[i]], 1);
    __syncthreads();
    if (tid == 0) {
      int off = 0, nt = 0;
      for (int e = 0; e < NE; ++e) {
        poff_s[e] = off;
        int tiles = (cnt[e] + BM - 1) / BM;
        for (int j = 0; j < tiles; ++j) { hdr[32 + nt] = e; hdr[80 + nt] = off + j * BM; ++nt; }
        off += tiles * BM;
      }
      poff_s[NE] = off;
      hdr[17] = nt;
      for (int e = 0; e < NE; ++e) hdr[e] = cnt[e];
      for (int e = 0; e <= NE; ++e) hdr[8 + e] = poff_s[e];
    }
    __syncthreads();
    for (int i = tid; i < PADSLOTS; i += 256) sorted[i] = -1;
    __syncthreads();
    for (int i = tid; i < NA; i += 256) {
      int e = sel[i];
      int p = atomicAdd(&fill[e], 1);
      sorted[poff_s[e] + p] = i;
    }
    return;
  }
  __shared__ u16 smem[2 * 64 * 72];
  int tensor = y >> 3, e = y & 7;
  const float* src = (tensor == 0) ? gw : uw;
  u16* dst = (tensor == 0) ? gT : uT;
  src += (size_t)e * NH * NI;
  dst += (size_t)e * NH * NI;
  int nb = blockIdx.x % 11, kb = blockIdx.x / 11;   // K=NH (16 kb), N=NI (11 nb)
  transcvt_stripe(src, dst, NH, NI, kb * 64, nb * 128, smem, tid);
}

// ---------------- K2: gemm1 blocks + down-convert blocks + out-zero blocks ----------------
// 1D grid: b<880 gemm1 (tile=b%40, n0=(b/40)*64); 880<=b<2288 down-convert; b>=2288 zero out.
__global__ __launch_bounds__(256, 4) void k2_gemm1(
    const u16* __restrict__ xbf, const u16* __restrict__ gT, const u16* __restrict__ uT,
    u16* __restrict__ hbuf, const int* __restrict__ hdr, const int* __restrict__ sorted,
    const float* __restrict__ dw, u16* __restrict__ dT, float* __restrict__ outz) {
  __shared__ u16 smem[16384];   // 32 KB, shared across roles
  int b = blockIdx.x;
  int tid = threadIdx.x;

  if (b >= 2288) {  // zero out: 64 blocks x 64KB
    int base = (b - 2288) * 16384;
    f4v z = {0.f, 0.f, 0.f, 0.f};
#pragma unroll
    for (int i = 0; i < 16; ++i)
      *(f4v*)&outz[base + (i * 256 + tid) * 4] = z;
    return;
  }
  if (b >= 880) {   // down-weight transpose-convert: 1408 stripes
    int idx = b - 880;
    int e = idx / 176, stripe = idx % 176;
    int nb = stripe % 8, kb = stripe / 8;           // K=NI (22 kb), N=NH (8 nb)
    const float* src = dw + (size_t)e * NI * NH;
    u16* dst = dT + (size_t)e * NI * NH;
    transcvt_stripe(src, dst, NI, NH, kb * 64, nb * 128, smem, tid);
    return;
  }

  // ---- gemm1: h = silu(x@gate) * (x@up), 128x64 tile, BK=64, XOR-swizzled LDS ----
  int tile = b % 40;
  if (tile >= hdr[17]) return;
  int e = hdr[32 + tile];
  int slot0 = hdr[80 + tile];
  int n0 = (b / 40) * 64;

  u16* sA  = smem;            // 128*64
  u16* sBg = smem + 8192;     // 64*64
  u16* sBu = smem + 12288;    // 64*64

  const u16* aptr[4];
  for (int s = 0; s < 4; ++s) {
    int idx = s * 256 + tid;
    int row = idx >> 3, c = idx & 7;
    int kc = c ^ (row & 7);
    int as = sorted[slot0 + row];
    int trow = (as >= 0) ? (as >> 2) : 0;
    aptr[s] = xbf + (size_t)trow * NH + kc * 8;
  }
  const u16 *bgp[2], *bup[2];
  for (int s = 0; s < 2; ++s) {
    int idx = s * 256 + tid;
    int n = idx >> 3, c = idx & 7;
    int kc = c ^ (n & 7);
    size_t o = ((size_t)e * NI + n0 + n) * NH + kc * 8;
    bgp[s] = gT + o; bup[s] = uT + o;
  }

  int lane = tid & 63, wave = tid >> 6;
  int wm = wave >> 1, wn = wave & 1;
  int l15 = lane & 15, quad = lane >> 4;
  int sw = l15 & 7;

  f32x4 accg[4][2] = {}; f32x4 accu[4][2] = {};

  for (int kt = 0; kt < NH / 64; ++kt) {
    int ko = kt * 64;
    for (int s = 0; s < 4; ++s) llds16(aptr[s] + ko, &sA[(s * 256 + tid) * 8]);
    for (int s = 0; s < 2; ++s) {
      llds16(bgp[s] + ko, &sBg[(s * 256 + tid) * 8]);
      llds16(bup[s] + ko, &sBu[(s * 256 + tid) * 8]);
    }
    __syncthreads();
    for (int ks = 0; ks < 2; ++ks) {
      int pos = ((ks * 4 + quad) ^ sw) * 8;
      short8 av[4], bg[2], bu[2];
      for (int mf = 0; mf < 4; ++mf)
        av[mf] = *(const short8*)&sA[(wm * 64 + mf * 16 + l15) * 64 + pos];
      for (int nf = 0; nf < 2; ++nf) {
        bg[nf] = *(const short8*)&sBg[(wn * 32 + nf * 16 + l15) * 64 + pos];
        bu[nf] = *(const short8*)&sBu[(wn * 32 + nf * 16 + l15) * 64 + pos];
      }
      for (int mf = 0; mf < 4; ++mf)
        for (int nf = 0; nf < 2; ++nf) {
          accg[mf][nf] = __builtin_amdgcn_mfma_f32_16x16x32_bf16(av[mf], bg[nf], accg[mf][nf], 0, 0, 0);
          accu[mf][nf] = __builtin_amdgcn_mfma_f32_16x16x32_bf16(av[mf], bu[nf], accu[mf][nf], 0, 0, 0);
        }
    }
    __syncthreads();
  }

  for (int mf = 0; mf < 4; ++mf)
    for (int nf = 0; nf < 2; ++nf)
      for (int r = 0; r < 4; ++r) {
        int row = wm * 64 + mf * 16 + quad * 4 + r;
        int col = n0 + wn * 32 + nf * 16 + l15;
        float g = accg[mf][nf][r], u = accu[mf][nf][r];
        float hv = (g / (1.f + __expf(-g))) * u;
        hbuf[(size_t)(slot0 + row) * NI + col] = f2b(hv);
      }
}

// ---------------- K3: down projection 128x128 + fused weighted atomic combine ----------------
__global__ __launch_bounds__(256, 4) void k3_gemm2(
    const u16* __restrict__ hbuf, const u16* __restrict__ dT,
    const float* __restrict__ rw, float* __restrict__ out,
    const int* __restrict__ hdr, const int* __restrict__ sorted) {
  int tile = blockIdx.x;
  if (tile >= hdr[17]) return;
  int e = hdr[32 + tile];
  int slot0 = hdr[80 + tile];
  int n0 = blockIdx.y * 128;
  int tid = threadIdx.x;

  __shared__ u16 sA[128 * 64];   // [m][k], swizzled
  __shared__ u16 sB[128 * 64];   // [n][k], swizzled

  const u16 *ap[4], *bp[4];
  for (int s = 0; s < 4; ++s) {
    int idx = s * 256 + tid;
    int r = idx >> 3, c = idx & 7;
    int kc = c ^ (r & 7);
    ap[s] = hbuf + (size_t)(slot0 + r) * NI + kc * 8;
    bp[s] = dT + ((size_t)e * NH + n0 + r) * NI + kc * 8;
  }

  int lane = tid & 63, wave = tid >> 6;
  int wm = wave >> 1, wn = wave & 1;
  int l15 = lane & 15, quad = lane >> 4;
  int sw = l15 & 7;

  f32x4 acc[4][4] = {};

  for (int kt = 0; kt < NI / 64; ++kt) {
    int ko = kt * 64;
    for (int s = 0; s < 4; ++s) llds16(ap[s] + ko, &sA[(s * 256 + tid) * 8]);
    for (int s = 0; s < 4; ++s) llds16(bp[s] + ko, &sB[(s * 256 + tid) * 8]);
    __syncthreads();
    for (int ks = 0; ks < 2; ++ks) {
      int pos = ((ks * 4 + quad) ^ sw) * 8;
      short8 av[4], bv[4];
      for (int mf = 0; mf < 4; ++mf)
        av[mf] = *(const short8*)&sA[(wm * 64 + mf * 16 + l15) * 64 + pos];
      for (int nf = 0; nf < 4; ++nf)
        bv[nf] = *(const short8*)&sB[(wn * 64 + nf * 16 + l15) * 64 + pos];
      for (int mf = 0; mf < 4; ++mf)
        for (int nf = 0; nf < 4; ++nf)
          acc[mf][nf] = __builtin_amdgcn_mfma_f32_16x16x32_bf16(av[mf], bv[nf], acc[mf][nf], 0, 0, 0);
    }
    __syncthreads();
  }

  // weighted combine: out[token] += rw[assignment] * down_row
  for (int mf = 0; mf < 4; ++mf) {
    int rowb = wm * 64 + mf * 16 + quad * 4;
    for (int r = 0; r < 4; ++r) {
      int as = sorted[slot0 + rowb + r];
      if (as < 0) continue;
      float w = rw[as];
      float* orow = out + (size_t)(as >> 2) * NH + n0 + wn * 64;
      for (int nf = 0; nf < 4; ++nf)
        atomicAdd(&orow[nf * 16 + l15], w * acc[mf][nf][r]);
    }
  }
}

extern "C" void kernel_launch(void* const* d_in, const int* in_sizes, int n_in,
                              void* d_out, int out_size, void* d_ws, size_t ws_size,
                              hipStream_t stream) {
  const float* hs  = (const float*)d_in[0];
  const float* rw  = (const float*)d_in[1];
  const float* gw  = (const float*)d_in[2];
  const float* uw  = (const float*)d_in[3];
  const float* dw  = (const float*)d_in[4];
  const int*   sel = (const int*)d_in[5];
  float* out = (float*)d_out;

  char* ws = (char*)d_ws;
  int*  hdr    = (int*)(ws + WS_HDR);
  int*  sorted = (int*)(ws + WS_SORT);
  u16*  xbf    = (u16*)(ws + WS_XBF);
  u16*  gT     = (u16*)(ws + WS_GT);
  u16*  uT     = (u16*)(ws + WS_UT);
  u16*  dT     = (u16*)(ws + WS_DT);
  u16*  hb     = (u16*)(ws + WS_HB);

  hipLaunchKernelGGL(k1_prep, dim3(176, 18), dim3(256), 0, stream,
                     gw, uw, hs, sel, gT, uT, xbf, hdr, sorted);
  hipLaunchKernelGGL(k2_gemm1, dim3(2352), dim3(256), 0, stream,
                     xbf, gT, uT, hb, hdr, sorted, dw, dT, out);
  hipLaunchKernelGGL(k3_gemm2, dim3(MAXTILES, NH / 128), dim3(256), 0, stream,
                     hb, dT, rw, out, hdr, sorted);
}

// Round 6
// 243.985 us; speedup vs baseline: 1.1589x; 1.0155x over previous
//
#include <hip/hip_runtime.h>
#include <hip/hip_bf16.h>
#include <cstdint>
#include <cstddef>

// Problem constants (DeepseekV3Experts: T=1024 H=1024 I=1408 E=8 K=4)
#define NE 8
#define NT 1024
#define NK 4
#define NH 1024
#define NI 1408
#define NA (NT * NK)      // 4096 assignments
#define BM 128            // row tile
#define MAXTILES 40
#define PADSLOTS 5120

typedef short short8 __attribute__((ext_vector_type(8)));
typedef float f32x4 __attribute__((ext_vector_type(4)));
typedef float f4v __attribute__((ext_vector_type(4)));   // clang-native for nontemporal builtins
typedef unsigned short u16;

// Workspace layout (bytes).
#define WS_HDR   0
#define WS_SORT  1024
#define WS_XBF   21504      // u16[NT*NH]
#define WS_GT    2118656    // u16[NE*NI*NH]  gate^T [E][I][H]
#define WS_UT    25187328   // u16[NE*NI*NH]  up^T
#define WS_DT    48256000   // u16[NE*NH*NI]  down^T [E][H][I]
#define WS_HB    71324672   // u16[PADSLOTS*NI]

__device__ __forceinline__ u16 f2b(float f) {
  union { float f; uint32_t u; } c; c.f = f;
  uint32_t u = c.u;
  return (u16)((u + 0x7FFFu + ((u >> 16) & 1u)) >> 16);  // RNE
}

__device__ __forceinline__ void llds16(const void* g, void* l) {
  __builtin_amdgcn_global_load_lds(
      (const __attribute__((address_space(1))) void*)g,
      (__attribute__((address_space(3))) void*)l, 16, 0, 0);
}

// Shared transpose-convert stripe: [K][N] fp32 -> [N][K] bf16, 64k x 128n per block.
// smem must hold 2*64*72 u16. 256 threads.
__device__ __forceinline__ void transcvt_stripe(const float* __restrict__ src,
                                                u16* __restrict__ dst,
                                                int K, int N, int k0, int n0,
                                                u16* smem, int tid) {
  u16 (*t2)[64][72] = (u16(*)[64][72])smem;
  int r = tid >> 4, c = tid & 15;          // 16 x 16 over (row, col16)
  f4v v[2][4];
#pragma unroll
  for (int t = 0; t < 2; ++t)
#pragma unroll
    for (int i = 0; i < 4; ++i)
      v[t][i] = __builtin_nontemporal_load(
          (const f4v*)&src[(size_t)(k0 + r + 16 * i) * N + n0 + t * 64 + c * 4]);
#pragma unroll
  for (int t = 0; t < 2; ++t)
#pragma unroll
    for (int i = 0; i < 4; ++i) {
      ushort4 o;
      o.x = f2b(v[t][i].x); o.y = f2b(v[t][i].y); o.z = f2b(v[t][i].z); o.w = f2b(v[t][i].w);
      *(ushort4*)&t2[t][r + 16 * i][c * 4] = o;
    }
  __syncthreads();
#pragma unroll
  for (int t = 0; t < 2; ++t)
#pragma unroll
    for (int i = 0; i < 2; ++i) {
      int idx = i * 256 + tid;
      int n = idx >> 3, kc = idx & 7;
      u16 o[8];
#pragma unroll
      for (int j = 0; j < 8; ++j) o[j] = t2[t][kc * 8 + j][n];
      *(short8*)&dst[(size_t)(n0 + t * 64 + n) * K + k0 + kc * 8] = *(const short8*)o;
    }
}

// ---------------- K1: bucket + gate/up transpose-convert + x convert + out zero ----------------
// Grid (176, 18): y<16 -> tensor=y>>3 (0 gate, 1 up), e=y&7, stripe=x (11 nb x 16 kb);
// y==16 -> x convert; y==17: x==0 bucket, 1<=x<=64 zero out (64 KB each).
__global__ __launch_bounds__(256) void k1_prep(
    const float* __restrict__ gw, const float* __restrict__ uw, const float* __restrict__ hs,
    const int* __restrict__ sel,
    u16* __restrict__ gT, u16* __restrict__ uT, u16* __restrict__ xbf,
    int* __restrict__ hdr, int* __restrict__ sorted, float* __restrict__ outz) {
  int tid = threadIdx.x;
  int y = blockIdx.y;
  if (y == 16) {  // hidden_states convert (1M elements)
    for (int i = blockIdx.x * 256 + tid; i * 4 < NT * NH; i += 176 * 256) {
      f4v v = __builtin_nontemporal_load((const f4v*)&hs[i * 4]);
      ushort4 o;
      o.x = f2b(v.x); o.y = f2b(v.y); o.z = f2b(v.z); o.w = f2b(v.w);
      *(ushort4*)&xbf[i * 4] = o;
    }
    return;
  }
  if (y == 17) {
    int x = blockIdx.x;
    if (x >= 1 && x <= 64) {  // zero out: 64 blocks x 64 KB
      int base = (x - 1) * 16384;
      f4v z = {0.f, 0.f, 0.f, 0.f};
#pragma unroll
      for (int i = 0; i < 16; ++i)
        *(f4v*)&outz[base + (i * 256 + tid) * 4] = z;
      return;
    }
    if (x != 0) return;
    // bucket (single block)
    __shared__ int cnt[NE], fill[NE], poff_s[NE + 1];
    if (tid < NE) { cnt[tid] = 0; fill[tid] = 0; }
    __syncthreads();
    for (int i = tid; i < NA; i += 256) atomicAdd(&cnt[sel[i]], 1);
    __syncthreads();
    if (tid == 0) {
      int off = 0, nt = 0;
      for (int e = 0; e < NE; ++e) {
        poff_s[e] = off;
        int tiles = (cnt[e] + BM - 1) / BM;
        for (int j = 0; j < tiles; ++j) { hdr[32 + nt] = e; hdr[80 + nt] = off + j * BM; ++nt; }
        off += tiles * BM;
      }
      poff_s[NE] = off;
      hdr[17] = nt;
      for (int e = 0; e < NE; ++e) hdr[e] = cnt[e];
      for (int e = 0; e <= NE; ++e) hdr[8 + e] = poff_s[e];
    }
    __syncthreads();
    for (int i = tid; i < PADSLOTS; i += 256) sorted[i] = -1;
    __syncthreads();
    for (int i = tid; i < NA; i += 256) {
      int e = sel[i];
      int p = atomicAdd(&fill[e], 1);
      sorted[poff_s[e] + p] = i;
    }
    return;
  }
  __shared__ u16 smem[2 * 64 * 72];
  int tensor = y >> 3, e = y & 7;
  const float* src = (tensor == 0) ? gw : uw;
  u16* dst = (tensor == 0) ? gT : uT;
  src += (size_t)e * NH * NI;
  dst += (size_t)e * NH * NI;
  int nb = blockIdx.x % 11, kb = blockIdx.x / 11;   // K=NH (16 kb), N=NI (11 nb)
  transcvt_stripe(src, dst, NH, NI, kb * 64, nb * 128, smem, tid);
}

// ---------------- K2: gemm1 (128x128 tile) + down-convert stripes ----------------
// 1D grid 1848: b<440 gemm1 (tile=b%40, n0=(b/40)*128); b>=440 down-convert stripes.
__global__ __launch_bounds__(256, 2) void k2_gemm1(
    const u16* __restrict__ xbf, const u16* __restrict__ gT, const u16* __restrict__ uT,
    u16* __restrict__ hbuf, const int* __restrict__ hdr, const int* __restrict__ sorted,
    const float* __restrict__ dw, u16* __restrict__ dT) {
  __shared__ u16 smem[24576];   // 48 KB shared across roles
  int b = blockIdx.x;
  int tid = threadIdx.x;

  if (b >= 440) {   // down-weight transpose-convert: 1408 stripes
    int idx = b - 440;
    int e = idx / 176, stripe = idx % 176;
    int nb = stripe % 8, kb = stripe / 8;           // K=NI (22 kb), N=NH (8 nb)
    const float* src = dw + (size_t)e * NI * NH;
    u16* dst = dT + (size_t)e * NI * NH;
    transcvt_stripe(src, dst, NI, NH, kb * 64, nb * 128, smem, tid);
    return;
  }

  // ---- gemm1: h = silu(x@gate) * (x@up), 128x128 tile, BK=64, XOR-swizzled LDS ----
  int tile = b % 40;
  if (tile >= hdr[17]) return;
  int e = hdr[32 + tile];
  int slot0 = hdr[80 + tile];
  int n0 = (b / 40) * 128;

  u16* sA  = smem;            // 128*64
  u16* sBg = smem + 8192;     // 128*64
  u16* sBu = smem + 16384;    // 128*64

  const u16* aptr[4];
  for (int s = 0; s < 4; ++s) {
    int idx = s * 256 + tid;
    int row = idx >> 3, c = idx & 7;
    int kc = c ^ (row & 7);
    int as = sorted[slot0 + row];
    int trow = (as >= 0) ? (as >> 2) : 0;
    aptr[s] = xbf + (size_t)trow * NH + kc * 8;
  }
  const u16 *bgp[4], *bup[4];
  for (int s = 0; s < 4; ++s) {
    int idx = s * 256 + tid;
    int n = idx >> 3, c = idx & 7;
    int kc = c ^ (n & 7);
    size_t o = ((size_t)e * NI + n0 + n) * NH + kc * 8;
    bgp[s] = gT + o; bup[s] = uT + o;
  }

  int lane = tid & 63, wave = tid >> 6;
  int wm = wave >> 1, wn = wave & 1;
  int l15 = lane & 15, quad = lane >> 4;
  int sw = l15 & 7;

  f32x4 accg[4][4] = {}; f32x4 accu[4][4] = {};

  for (int kt = 0; kt < NH / 64; ++kt) {
    int ko = kt * 64;
    for (int s = 0; s < 4; ++s) llds16(aptr[s] + ko, &sA[(s * 256 + tid) * 8]);
    for (int s = 0; s < 4; ++s) llds16(bgp[s] + ko, &sBg[(s * 256 + tid) * 8]);
    for (int s = 0; s < 4; ++s) llds16(bup[s] + ko, &sBu[(s * 256 + tid) * 8]);
    __syncthreads();
    for (int ks = 0; ks < 2; ++ks) {
      int pos = ((ks * 4 + quad) ^ sw) * 8;
      short8 av[4], bg[4], bu[4];
      for (int mf = 0; mf < 4; ++mf)
        av[mf] = *(const short8*)&sA[(wm * 64 + mf * 16 + l15) * 64 + pos];
      for (int nf = 0; nf < 4; ++nf) {
        bg[nf] = *(const short8*)&sBg[(wn * 64 + nf * 16 + l15) * 64 + pos];
        bu[nf] = *(const short8*)&sBu[(wn * 64 + nf * 16 + l15) * 64 + pos];
      }
      for (int mf = 0; mf < 4; ++mf)
        for (int nf = 0; nf < 4; ++nf) {
          accg[mf][nf] = __builtin_amdgcn_mfma_f32_16x16x32_bf16(av[mf], bg[nf], accg[mf][nf], 0, 0, 0);
          accu[mf][nf] = __builtin_amdgcn_mfma_f32_16x16x32_bf16(av[mf], bu[nf], accu[mf][nf], 0, 0, 0);
        }
    }
    __syncthreads();
  }

  for (int mf = 0; mf < 4; ++mf)
    for (int nf = 0; nf < 4; ++nf)
      for (int r = 0; r < 4; ++r) {
        int row = wm * 64 + mf * 16 + quad * 4 + r;
        int col = n0 + wn * 64 + nf * 16 + l15;
        float g = accg[mf][nf][r], u = accu[mf][nf][r];
        float hv = (g / (1.f + __expf(-g))) * u;
        hbuf[(size_t)(slot0 + row) * NI + col] = f2b(hv);
      }
}

// ---------------- K3: down projection 128x128 + fused weighted atomic combine ----------------
__global__ __launch_bounds__(256, 4) void k3_gemm2(
    const u16* __restrict__ hbuf, const u16* __restrict__ dT,
    const float* __restrict__ rw, float* __restrict__ out,
    const int* __restrict__ hdr, const int* __restrict__ sorted) {
  int tile = blockIdx.x;
  if (tile >= hdr[17]) return;
  int e = hdr[32 + tile];
  int slot0 = hdr[80 + tile];
  int n0 = blockIdx.y * 128;
  int tid = threadIdx.x;

  __shared__ u16 sA[128 * 64];   // [m][k], swizzled
  __shared__ u16 sB[128 * 64];   // [n][k], swizzled

  const u16 *ap[4], *bp[4];
  for (int s = 0; s < 4; ++s) {
    int idx = s * 256 + tid;
    int r = idx >> 3, c = idx & 7;
    int kc = c ^ (r & 7);
    ap[s] = hbuf + (size_t)(slot0 + r) * NI + kc * 8;
    bp[s] = dT + ((size_t)e * NH + n0 + r) * NI + kc * 8;
  }

  int lane = tid & 63, wave = tid >> 6;
  int wm = wave >> 1, wn = wave & 1;
  int l15 = lane & 15, quad = lane >> 4;
  int sw = l15 & 7;

  f32x4 acc[4][4] = {};

  for (int kt = 0; kt < NI / 64; ++kt) {
    int ko = kt * 64;
    for (int s = 0; s < 4; ++s) llds16(ap[s] + ko, &sA[(s * 256 + tid) * 8]);
    for (int s = 0; s < 4; ++s) llds16(bp[s] + ko, &sB[(s * 256 + tid) * 8]);
    __syncthreads();
    for (int ks = 0; ks < 2; ++ks) {
      int pos = ((ks * 4 + quad) ^ sw) * 8;
      short8 av[4], bv[4];
      for (int mf = 0; mf < 4; ++mf)
        av[mf] = *(const short8*)&sA[(wm * 64 + mf * 16 + l15) * 64 + pos];
      for (int nf = 0; nf < 4; ++nf)
        bv[nf] = *(const short8*)&sB[(wn * 64 + nf * 16 + l15) * 64 + pos];
      for (int mf = 0; mf < 4; ++mf)
        for (int nf = 0; nf < 4; ++nf)
          acc[mf][nf] = __builtin_amdgcn_mfma_f32_16x16x32_bf16(av[mf], bv[nf], acc[mf][nf], 0, 0, 0);
    }
    __syncthreads();
  }

  // weighted combine: out[token] += rw[assignment] * down_row
  for (int mf = 0; mf < 4; ++mf) {
    int rowb = wm * 64 + mf * 16 + quad * 4;
    for (int r = 0; r < 4; ++r) {
      int as = sorted[slot0 + rowb + r];
      if (as < 0) continue;
      float w = rw[as];
      float* orow = out + (size_t)(as >> 2) * NH + n0 + wn * 64;
      for (int nf = 0; nf < 4; ++nf)
        atomicAdd(&orow[nf * 16 + l15], w * acc[mf][nf][r]);
    }
  }
}

extern "C" void kernel_launch(void* const* d_in, const int* in_sizes, int n_in,
                              void* d_out, int out_size, void* d_ws, size_t ws_size,
                              hipStream_t stream) {
  const float* hs  = (const float*)d_in[0];
  const float* rw  = (const float*)d_in[1];
  const float* gw  = (const float*)d_in[2];
  const float* uw  = (const float*)d_in[3];
  const float* dw  = (const float*)d_in[4];
  const int*   sel = (const int*)d_in[5];
  float* out = (float*)d_out;

  char* ws = (char*)d_ws;
  int*  hdr    = (int*)(ws + WS_HDR);
  int*  sorted = (int*)(ws + WS_SORT);
  u16*  xbf    = (u16*)(ws + WS_XBF);
  u16*  gT     = (u16*)(ws + WS_GT);
  u16*  uT     = (u16*)(ws + WS_UT);
  u16*  dT     = (u16*)(ws + WS_DT);
  u16*  hb     = (u16*)(ws + WS_HB);

  hipLaunchKernelGGL(k1_prep, dim3(176, 18), dim3(256), 0, stream,
                     gw, uw, hs, sel, gT, uT, xbf, hdr, sorted, out);
  hipLaunchKernelGGL(k2_gemm1, dim3(1848), dim3(256), 0, stream,
                     xbf, gT, uT, hb, hdr, sorted, dw, dT);
  hipLaunchKernelGGL(k3_gemm2, dim3(MAXTILES, NH / 128), dim3(256), 0, stream,
                     hb, dT, rw, out, hdr, sorted);
}